// Round 9
// baseline (151.615 us; speedup 1.0000x reference)
//
#include <hip/hip_runtime.h>
#include <hip/hip_bf16.h>

typedef short short8 __attribute__((ext_vector_type(8)));
typedef float floatx4 __attribute__((ext_vector_type(4)));
typedef unsigned short ushort8_t __attribute__((ext_vector_type(8)));

#define NN 2000      // nodes
#define NE 40000     // edges
#define NB 4         // batch
#define T_IN 34
#define TP 32        // output time steps
#define NBT (NB * TP)         // 128 bt slices
#define NPOS (NB * TP * NN)   // 256000 positions
#define CAP 96                // padded-CSR capacity (max in-deg ~45, Poisson(20))
#define NEB 157               // edge blocks (first in grid)

// ws layout (float offsets):
//  deg:     [0, 2048)            float (memset 0)
//  cursor:  [2048, 4096)         int   (memset 0)
//  pcsr:    [4096, 388096)       int2{src, bits(ew)} x (2000*96)
//  h2:      [388096 ..)          bf16/ushort, 2000*128*32 = 16.4 MB

// ---------- bf16 helpers ----------
__device__ inline unsigned short f2bf(float x) {        // RNE (for h2 store)
    unsigned int u = __float_as_uint(x);
    u = u + 0x7fff + ((u >> 16) & 1);
    return (unsigned short)(u >> 16);
}
// Truncation split: hi = top16(x) (exact bf16 trunc); lo = x - hi (EXACT f32).
__device__ inline void splitPair(float x0, float x1, unsigned& hi, unsigned& lo) {
    unsigned u0 = __float_as_uint(x0), u1 = __float_as_uint(x1);
    hi = __builtin_amdgcn_perm(u1, u0, 0x07060302u);   // [top16(x1), top16(x0)]
    float r0 = x0 - __uint_as_float(u0 & 0xffff0000u);
    float r1 = x1 - __uint_as_float(u1 & 0xffff0000u);
    lo = __builtin_amdgcn_perm(__float_as_uint(r1), __float_as_uint(r0), 0x07060302u);
}
__device__ inline void splitA8(const float* v, short8& hi, short8& lo) {
    union { unsigned u[4]; short8 s; } H, L;
#pragma unroll
    for (int j = 0; j < 4; ++j) {
        unsigned h_, l_;
        splitPair(v[2 * j], v[2 * j + 1], h_, l_);
        H.u[j] = h_; L.u[j] = l_;
    }
    hi = H.s; lo = L.s;
}

// ---- edge blocks (0..156): deg + padded-CSR fill; conv blocks (157..1156) ---
// Edge blocks dispatch FIRST so their atomics complete under the conv ramp.
__global__ __launch_bounds__(256) void conv_deg_kernel(
        const float* __restrict__ x,
        const float* __restrict__ w1, const float* __restrict__ b1,
        const float* __restrict__ w2, const float* __restrict__ b2,
        unsigned short* __restrict__ h2,
        const int* __restrict__ row, const int* __restrict__ col,
        const float* __restrict__ ew,
        float* __restrict__ deg, int* __restrict__ cursor,
        int2* __restrict__ pcsr) {
    if (blockIdx.x < NEB) {
        int e = blockIdx.x * 256 + threadIdx.x;
        if (e < NE) {
            int c = col[e], r = row[e];
            float w = ew[e];
            atomicAdd(&deg[c], w);
            int slot = atomicAdd(&cursor[c], 1);
            if (slot < CAP) pcsr[c * CAP + slot] = make_int2(r, __float_as_int(w));
        }
        return;
    }

    int l = threadIdx.x & 63;
    int w = threadIdx.x >> 6;
    int colL = l & 15, q = l >> 4;

    // B fragments [gate][dc-half][tap], trunc-split hi/lo. Once per wave.
    short8 Whi[2][2][2], Wlo[2][2][2];
#pragma unroll
    for (int g = 0; g < 2; ++g) {
        const float* wp = g ? w2 : w1;
#pragma unroll
        for (int d = 0; d < 2; ++d)
#pragma unroll
        for (int tap = 0; tap < 2; ++tap) {
            float wv[8];
#pragma unroll
            for (int j = 0; j < 8; ++j)
                wv[j] = wp[(d * 16 + colL) * 64 + (q * 8 + j) * 2 + tap];
            splitA8(wv, Whi[g][d][tap], Wlo[g][d][tap]);
        }
    }
    float bias[2][2] = { { b1[colL], b1[colL + 16] }, { b2[colL], b2[colL + 16] } };

    for (int i = 0; i < 4; ++i) {
        int tile = (blockIdx.x - NEB) * 16 + w * 4 + i;
        int pos0 = tile * 16;
        int bt = pos0 / 2000;
        int n0 = pos0 - bt * 2000;
        int b_ = bt >> 5, t_ = bt & 31;
        const float* xa = x + (((b_ * T_IN + t_) * NN) + n0 + colL) * 32 + q * 8;
        const float* xb = xa + 2 * NN * 32;   // dilation-2 tap
        float va[8], vb[8];
        *(float4*)va       = *(const float4*)xa;
        *(float4*)(va + 4) = *(const float4*)(xa + 4);
        *(float4*)vb       = *(const float4*)xb;
        *(float4*)(vb + 4) = *(const float4*)(xb + 4);
        short8 Ahi0, Alo0, Ahi1, Alo1;
        splitA8(va, Ahi0, Alo0);
        splitA8(vb, Ahi1, Alo1);

        floatx4 acc[2][2];
#pragma unroll
        for (int g = 0; g < 2; ++g)
#pragma unroll
        for (int d = 0; d < 2; ++d) {
            float bv = bias[g][d];
            floatx4 a = { bv, bv, bv, bv };
            a = __builtin_amdgcn_mfma_f32_16x16x32_bf16(Ahi0, Whi[g][d][0], a, 0, 0, 0);
            a = __builtin_amdgcn_mfma_f32_16x16x32_bf16(Ahi1, Whi[g][d][1], a, 0, 0, 0);
            a = __builtin_amdgcn_mfma_f32_16x16x32_bf16(Alo0, Whi[g][d][0], a, 0, 0, 0);
            a = __builtin_amdgcn_mfma_f32_16x16x32_bf16(Alo1, Whi[g][d][1], a, 0, 0, 0);
            a = __builtin_amdgcn_mfma_f32_16x16x32_bf16(Ahi0, Wlo[g][d][0], a, 0, 0, 0);
            a = __builtin_amdgcn_mfma_f32_16x16x32_bf16(Ahi1, Wlo[g][d][1], a, 0, 0, 0);
            acc[g][d] = a;
        }

#pragma unroll
        for (int d = 0; d < 2; ++d)
#pragma unroll
        for (int r = 0; r < 4; ++r) {
            float g1 = acc[0][d][r];
            float g2 = acc[1][d][r];
            float e2 = __expf(2.0f * g1);
            float th = (e2 - 1.0f) / (e2 + 1.0f);
            float sg = 1.0f / (1.0f + __expf(-g2));
            float h = th * sg;
            int n = n0 + q * 4 + r;
            h2[(n * NBT + bt) * 32 + d * 16 + colL] = f2bf(h);
        }
    }
}

// bf16x8 (as 4 dwords) -> float2[4] accumulate with packed math
__device__ inline void acc8(float2* a2, const ushort8_t& v, float nr) {
    union { ushort8_t s; unsigned u[4]; } U; U.s = v;
#pragma unroll
    for (int j = 0; j < 4; ++j) {
        float2 vv;
        vv.x = __uint_as_float(U.u[j] << 16);
        vv.y = __uint_as_float(U.u[j] & 0xffff0000u);
        a2[j].x += vv.x * nr;
        a2[j].y += vv.y * nr;
    }
}

// ---------- fused aggregation + gcn ----------
// 2 waves per (node, cp): even/odd edge-halves (stride-2 walk), partials
// combined in LDS. Block = 2 nodes x 2 halves, cp = blockIdx%8 (XCD slice,
// 2MB h2 slice L2-resident). Per edge: ONE coalesced 1KB bf16 gather.
__global__ __launch_bounds__(256) void agg_gcn_kernel(
        const unsigned short* __restrict__ h2,
        const float* __restrict__ deg, const int* __restrict__ cursor,
        const int2* __restrict__ pcsr,
        const float* __restrict__ gw, const float* __restrict__ gb,
        float* __restrict__ out) {
    __shared__ float st[64 * 36];   // 4 slabs of 16x32, stride 36
    int l = threadIdx.x & 63;
    int wv = threadIdx.x >> 6;           // 0..3
    int b = blockIdx.x;
    int cp = b & 7;                      // 16-bt chunk-pair == XCD slice
    int n = (b >> 3) * 2 + (wv >> 1);    // waves 0,1 -> n0; 2,3 -> n1
    int hf = wv & 1;                     // edge-half (even/odd slots)
    int colL = l & 15, q = l >> 4;

    // gcn B fragments (trunc split) — latency hidden under gather loop
    short8 Bhi[2], Blo[2];
#pragma unroll
    for (int d = 0; d < 2; ++d) {
        float wv8[8];
#pragma unroll
        for (int j = 0; j < 8; ++j)
            wv8[j] = gw[(q * 8 + j) * 32 + d * 16 + colL];
        splitA8(wv8, Bhi[d], Blo[d]);
    }
    float gb0 = gb[colL], gb1 = gb[colL + 16];

    const unsigned short* base = h2 + cp * 512 + l * 8;
    float dn = rsqrtf(deg[n] + 1.0f);
    float2 a2[4] = { {0,0}, {0,0}, {0,0}, {0,0} };
    if (hf == 0) {                        // self loop only in even wave
        ushort8_t sv = *(const ushort8_t*)(base + (size_t)n * 4096);
        acc8(a2, sv, dn * dn);
    }
    int cnt = cursor[n]; if (cnt > CAP) cnt = CAP;
    const int2* slots = pcsr + n * CAP;
    int i = hf;
    for (; i + 6 < cnt; i += 8) {         // 4 edges (stride 2) per iter
        int2 e0 = slots[i], e1 = slots[i + 2], e2 = slots[i + 4], e3 = slots[i + 6];
        float n0 = rsqrtf(deg[e0.x] + 1.0f) * __int_as_float(e0.y) * dn;
        float n1 = rsqrtf(deg[e1.x] + 1.0f) * __int_as_float(e1.y) * dn;
        float n2 = rsqrtf(deg[e2.x] + 1.0f) * __int_as_float(e2.y) * dn;
        float n3 = rsqrtf(deg[e3.x] + 1.0f) * __int_as_float(e3.y) * dn;
        ushort8_t v0 = *(const ushort8_t*)(base + (size_t)e0.x * 4096);
        ushort8_t v1 = *(const ushort8_t*)(base + (size_t)e1.x * 4096);
        ushort8_t v2 = *(const ushort8_t*)(base + (size_t)e2.x * 4096);
        ushort8_t v3 = *(const ushort8_t*)(base + (size_t)e3.x * 4096);
        acc8(a2, v0, n0); acc8(a2, v1, n1); acc8(a2, v2, n2); acc8(a2, v3, n3);
    }
    for (; i < cnt; i += 2) {
        int2 e0 = slots[i];
        float n0 = rsqrtf(deg[e0.x] + 1.0f) * __int_as_float(e0.y) * dn;
        ushort8_t v0 = *(const ushort8_t*)(base + (size_t)e0.x * 4096);
        acc8(a2, v0, n0);
    }

    // stage partials: lane l holds (bt_local = l>>2, c = (l&3)*8 .. +8)
    float* dst = &st[(wv * 16 + (l >> 2)) * 36 + (l & 3) * 8];
    *(float4*)dst       = make_float4(a2[0].x, a2[0].y, a2[1].x, a2[1].y);
    *(float4*)(dst + 4) = make_float4(a2[2].x, a2[2].y, a2[3].x, a2[3].y);
    __syncthreads();

    // even waves combine their pair of slabs and run the gcn MFMA
    if (hf == 0) {
        float av[8];
        const float* ap0 = &st[(wv * 16 + colL) * 36 + q * 8];
        const float* ap1 = ap0 + 16 * 36;
        float4 x0 = *(const float4*)ap0, x1 = *(const float4*)(ap0 + 4);
        float4 y0 = *(const float4*)ap1, y1 = *(const float4*)(ap1 + 4);
        av[0] = x0.x + y0.x; av[1] = x0.y + y0.y; av[2] = x0.z + y0.z; av[3] = x0.w + y0.w;
        av[4] = x1.x + y1.x; av[5] = x1.y + y1.y; av[6] = x1.z + y1.z; av[7] = x1.w + y1.w;
        short8 Ahi, Alo;
        splitA8(av, Ahi, Alo);
        floatx4 z = { 0.f, 0.f, 0.f, 0.f };
        floatx4 acc0 = z, acc1 = z;
        acc0 = __builtin_amdgcn_mfma_f32_16x16x32_bf16(Ahi, Bhi[0], acc0, 0, 0, 0);
        acc0 = __builtin_amdgcn_mfma_f32_16x16x32_bf16(Alo, Bhi[0], acc0, 0, 0, 0);
        acc0 = __builtin_amdgcn_mfma_f32_16x16x32_bf16(Ahi, Blo[0], acc0, 0, 0, 0);
        acc1 = __builtin_amdgcn_mfma_f32_16x16x32_bf16(Ahi, Bhi[1], acc1, 0, 0, 0);
        acc1 = __builtin_amdgcn_mfma_f32_16x16x32_bf16(Alo, Bhi[1], acc1, 0, 0, 0);
        acc1 = __builtin_amdgcn_mfma_f32_16x16x32_bf16(Ahi, Blo[1], acc1, 0, 0, 0);
#pragma unroll
        for (int r = 0; r < 4; ++r) {
            int btl = q * 4 + r;
            size_t o = ((size_t)(cp * 16 + btl) * NN + n) << 5;
            out[o + colL]      = acc0[r] + gb0;
            out[o + colL + 16] = acc1[r] + gb1;
        }
    }
}

extern "C" void kernel_launch(void* const* d_in, const int* in_sizes, int n_in,
                              void* d_out, int out_size, void* d_ws, size_t ws_size,
                              hipStream_t stream) {
    const float* x   = (const float*)d_in[0];
    const int*   ei  = (const int*)d_in[1];
    const float* ew  = (const float*)d_in[2];
    const float* g1w = (const float*)d_in[3];
    const float* g1b = (const float*)d_in[4];
    const float* g2w = (const float*)d_in[5];
    const float* g2b = (const float*)d_in[6];
    const float* gcw = (const float*)d_in[7];
    const float* gcb = (const float*)d_in[8];
    float* out = (float*)d_out;

    float* wsf      = (float*)d_ws;
    float* deg      = wsf;
    int*   cursor   = (int*)(wsf + 2048);
    int2*  pcsr     = (int2*)(wsf + 4096);
    unsigned short* h2 = (unsigned short*)(wsf + 388096);

    const int* row = ei;
    const int* col = ei + NE;

    hipMemsetAsync(wsf, 0, 4096 * sizeof(float), stream);   // deg + cursor
    hipLaunchKernelGGL(conv_deg_kernel, dim3(NEB + 1000), dim3(256), 0, stream,
                       x, g1w, g1b, g2w, g2b, h2, row, col, ew,
                       deg, cursor, pcsr);
    hipLaunchKernelGGL(agg_gcn_kernel, dim3(8000), dim3(256), 0, stream,
                       h2, deg, cursor, pcsr, gcw, gcb, out);
}

// Round 10
// 150.051 us; speedup vs baseline: 1.0104x; 1.0104x over previous
//
#include <hip/hip_runtime.h>
#include <hip/hip_bf16.h>

typedef short short8 __attribute__((ext_vector_type(8)));
typedef float floatx4 __attribute__((ext_vector_type(4)));
typedef unsigned short ushort8_t __attribute__((ext_vector_type(8)));

#define NN 2000      // nodes
#define NE 40000     // edges
#define NB 4         // batch
#define T_IN 34
#define TP 32        // output time steps
#define NBT (NB * TP)         // 128 bt slices
#define NPOS (NB * TP * NN)   // 256000 positions
#define CAP 96                // padded-CSR capacity (max in-deg ~45, Poisson(20))
#define NCB 2000              // conv blocks (2 tiles per wave)

// ws layout (float offsets):
//  deg:     [0, 2048)            float (memset 0)
//  cursor:  [2048, 4096)         int   (memset 0)
//  pcsr:    [4096, 388096)       int2{src, bits(ew)} x (2000*96)
//  h2:      [388096 ..)          bf16/ushort, 2000*128*32 = 16.4 MB

// ---------- bf16 helpers ----------
__device__ inline unsigned short f2bf(float x) {        // RNE (for h2 store)
    unsigned int u = __float_as_uint(x);
    u = u + 0x7fff + ((u >> 16) & 1);
    return (unsigned short)(u >> 16);
}
// Truncation split: hi = top16(x) (exact bf16 trunc); lo = x - hi (EXACT f32).
__device__ inline void splitPair(float x0, float x1, unsigned& hi, unsigned& lo) {
    unsigned u0 = __float_as_uint(x0), u1 = __float_as_uint(x1);
    hi = __builtin_amdgcn_perm(u1, u0, 0x07060302u);   // [top16(x1), top16(x0)]
    float r0 = x0 - __uint_as_float(u0 & 0xffff0000u);
    float r1 = x1 - __uint_as_float(u1 & 0xffff0000u);
    lo = __builtin_amdgcn_perm(__float_as_uint(r1), __float_as_uint(r0), 0x07060302u);
}
__device__ inline void splitA8(const float* v, short8& hi, short8& lo) {
    union { unsigned u[4]; short8 s; } H, L;
#pragma unroll
    for (int j = 0; j < 4; ++j) {
        unsigned h_, l_;
        splitPair(v[2 * j], v[2 * j + 1], h_, l_);
        H.u[j] = h_; L.u[j] = l_;
    }
    hi = H.s; lo = L.s;
}

// ---- conv (blocks 0..1999, 2 tiles/wave) + edge blocks (2000..2156) ----
__global__ __launch_bounds__(256, 4) void conv_deg_kernel(
        const float* __restrict__ x,
        const float* __restrict__ w1, const float* __restrict__ b1,
        const float* __restrict__ w2, const float* __restrict__ b2,
        unsigned short* __restrict__ h2,
        const int* __restrict__ row, const int* __restrict__ col,
        const float* __restrict__ ew,
        float* __restrict__ deg, int* __restrict__ cursor,
        int2* __restrict__ pcsr) {
    if (blockIdx.x >= NCB) {
        int e = (blockIdx.x - NCB) * 256 + threadIdx.x;
        if (e < NE) {
            int c = col[e], r = row[e];
            float w = ew[e];
            atomicAdd(&deg[c], w);
            int slot = atomicAdd(&cursor[c], 1);
            if (slot < CAP) pcsr[c * CAP + slot] = make_int2(r, __float_as_int(w));
        }
        return;
    }

    int l = threadIdx.x & 63;
    int w = threadIdx.x >> 6;
    int colL = l & 15, q = l >> 4;

    // B fragments [gate][dc-half][tap], trunc-split hi/lo. Once per wave.
    short8 Whi[2][2][2], Wlo[2][2][2];
#pragma unroll
    for (int g = 0; g < 2; ++g) {
        const float* wp = g ? w2 : w1;
#pragma unroll
        for (int d = 0; d < 2; ++d)
#pragma unroll
        for (int tap = 0; tap < 2; ++tap) {
            float wv[8];
#pragma unroll
            for (int j = 0; j < 8; ++j)
                wv[j] = wp[(d * 16 + colL) * 64 + (q * 8 + j) * 2 + tap];
            splitA8(wv, Whi[g][d][tap], Wlo[g][d][tap]);
        }
    }
    float bias[2][2] = { { b1[colL], b1[colL + 16] }, { b2[colL], b2[colL + 16] } };

    // ---- load BOTH tiles' inputs up front (software pipeline) ----
    int tile0 = blockIdx.x * 8 + w * 2;
    float va[2][8], vb[2][8];
    int n0s[2], bts[2];
#pragma unroll
    for (int t = 0; t < 2; ++t) {
        int pos0 = (tile0 + t) * 16;
        int bt = pos0 / 2000;
        int n0 = pos0 - bt * 2000;
        n0s[t] = n0; bts[t] = bt;
        int b_ = bt >> 5, t_ = bt & 31;
        const float* xa = x + (((b_ * T_IN + t_) * NN) + n0 + colL) * 32 + q * 8;
        const float* xb = xa + 2 * NN * 32;   // dilation-2 tap
        *(float4*)&va[t][0] = *(const float4*)xa;
        *(float4*)&va[t][4] = *(const float4*)(xa + 4);
        *(float4*)&vb[t][0] = *(const float4*)xb;
        *(float4*)&vb[t][4] = *(const float4*)(xb + 4);
    }

#pragma unroll
    for (int t = 0; t < 2; ++t) {
        short8 Ahi0, Alo0, Ahi1, Alo1;
        splitA8(va[t], Ahi0, Alo0);
        splitA8(vb[t], Ahi1, Alo1);

        floatx4 acc[2][2];
#pragma unroll
        for (int g = 0; g < 2; ++g)
#pragma unroll
        for (int d = 0; d < 2; ++d) {
            float bv = bias[g][d];
            floatx4 a = { bv, bv, bv, bv };
            a = __builtin_amdgcn_mfma_f32_16x16x32_bf16(Ahi0, Whi[g][d][0], a, 0, 0, 0);
            a = __builtin_amdgcn_mfma_f32_16x16x32_bf16(Ahi1, Whi[g][d][1], a, 0, 0, 0);
            a = __builtin_amdgcn_mfma_f32_16x16x32_bf16(Alo0, Whi[g][d][0], a, 0, 0, 0);
            a = __builtin_amdgcn_mfma_f32_16x16x32_bf16(Alo1, Whi[g][d][1], a, 0, 0, 0);
            a = __builtin_amdgcn_mfma_f32_16x16x32_bf16(Ahi0, Wlo[g][d][0], a, 0, 0, 0);
            a = __builtin_amdgcn_mfma_f32_16x16x32_bf16(Ahi1, Wlo[g][d][1], a, 0, 0, 0);
            acc[g][d] = a;
        }

        int n0 = n0s[t], bt = bts[t];
#pragma unroll
        for (int d = 0; d < 2; ++d)
#pragma unroll
        for (int r = 0; r < 4; ++r) {
            float g1 = acc[0][d][r];
            float g2 = acc[1][d][r];
            float e2 = __expf(2.0f * g1);
            float th = (e2 - 1.0f) * __builtin_amdgcn_rcpf(e2 + 1.0f);   // tanh
            float sg = __builtin_amdgcn_rcpf(1.0f + __expf(-g2));        // sigmoid
            float h = th * sg;
            int n = n0 + q * 4 + r;
            h2[(n * NBT + bt) * 32 + d * 16 + colL] = f2bf(h);
        }
    }
}

// bf16x8 (as 4 dwords) -> float2[4] accumulate with packed math
__device__ inline void acc8(float2* a2, const ushort8_t& v, float nr) {
    union { ushort8_t s; unsigned u[4]; } U; U.s = v;
#pragma unroll
    for (int j = 0; j < 4; ++j) {
        float2 vv;
        vv.x = __uint_as_float(U.u[j] << 16);
        vv.y = __uint_as_float(U.u[j] & 0xffff0000u);
        a2[j].x += vv.x * nr;
        a2[j].y += vv.y * nr;
    }
}

// ---------- fused aggregation + gcn (R8 form) ----------
// Wave = (node, chunk-pair of 16 bt). Per edge: wave-uniform slot load
// {src, ew}, norm on the fly from completed deg, ONE coalesced 1KB bf16
// gather. blockIdx%8 XCD swizzle keeps each 2MB h2 slice L2-resident.
__global__ __launch_bounds__(256) void agg_gcn_kernel(
        const unsigned short* __restrict__ h2,
        const float* __restrict__ deg, const int* __restrict__ cursor,
        const int2* __restrict__ pcsr,
        const float* __restrict__ gw, const float* __restrict__ gb,
        float* __restrict__ out) {
    __shared__ float st[64 * 36];   // 4 tiles of 16x32, stride 36
    int l = threadIdx.x & 63;
    int wv = threadIdx.x >> 6;
    int b = blockIdx.x;
    int cp = b & 7;                      // chunk-pair (16 bt) == XCD slice
    int n = (b >> 3) * 4 + wv;           // 0..1999
    int colL = l & 15, q = l >> 4;

    // gcn B fragments (trunc split) — latency hidden under gather loop
    short8 Bhi[2], Blo[2];
#pragma unroll
    for (int d = 0; d < 2; ++d) {
        float wv8[8];
#pragma unroll
        for (int j = 0; j < 8; ++j)
            wv8[j] = gw[(q * 8 + j) * 32 + d * 16 + colL];
        splitA8(wv8, Bhi[d], Blo[d]);
    }
    float gb0 = gb[colL], gb1 = gb[colL + 16];

    const unsigned short* base = h2 + cp * 512 + l * 8;
    float dn = rsqrtf(deg[n] + 1.0f);
    float w0 = dn * dn;                  // self-loop norm
    float2 a2[4] = { {0,0}, {0,0}, {0,0}, {0,0} };
    {
        ushort8_t sv = *(const ushort8_t*)(base + (size_t)n * 4096);
        acc8(a2, sv, w0);
    }
    int cnt = cursor[n]; if (cnt > CAP) cnt = CAP;
    const int2* slots = pcsr + n * CAP;
    int i = 0;
    for (; i + 8 <= cnt; i += 8) {
        int2 e0 = slots[i],     e1 = slots[i + 1], e2 = slots[i + 2], e3 = slots[i + 3];
        int2 e4 = slots[i + 4], e5 = slots[i + 5], e6 = slots[i + 6], e7 = slots[i + 7];
        float n0 = rsqrtf(deg[e0.x] + 1.0f) * __int_as_float(e0.y) * dn;
        float n1 = rsqrtf(deg[e1.x] + 1.0f) * __int_as_float(e1.y) * dn;
        float n2 = rsqrtf(deg[e2.x] + 1.0f) * __int_as_float(e2.y) * dn;
        float n3 = rsqrtf(deg[e3.x] + 1.0f) * __int_as_float(e3.y) * dn;
        float n4 = rsqrtf(deg[e4.x] + 1.0f) * __int_as_float(e4.y) * dn;
        float n5 = rsqrtf(deg[e5.x] + 1.0f) * __int_as_float(e5.y) * dn;
        float n6 = rsqrtf(deg[e6.x] + 1.0f) * __int_as_float(e6.y) * dn;
        float n7 = rsqrtf(deg[e7.x] + 1.0f) * __int_as_float(e7.y) * dn;
        ushort8_t v0 = *(const ushort8_t*)(base + (size_t)e0.x * 4096);
        ushort8_t v1 = *(const ushort8_t*)(base + (size_t)e1.x * 4096);
        ushort8_t v2 = *(const ushort8_t*)(base + (size_t)e2.x * 4096);
        ushort8_t v3 = *(const ushort8_t*)(base + (size_t)e3.x * 4096);
        ushort8_t v4 = *(const ushort8_t*)(base + (size_t)e4.x * 4096);
        ushort8_t v5 = *(const ushort8_t*)(base + (size_t)e5.x * 4096);
        ushort8_t v6 = *(const ushort8_t*)(base + (size_t)e6.x * 4096);
        ushort8_t v7 = *(const ushort8_t*)(base + (size_t)e7.x * 4096);
        acc8(a2, v0, n0); acc8(a2, v1, n1); acc8(a2, v2, n2); acc8(a2, v3, n3);
        acc8(a2, v4, n4); acc8(a2, v5, n5); acc8(a2, v6, n6); acc8(a2, v7, n7);
    }
    for (; i + 4 <= cnt; i += 4) {
        int2 e0 = slots[i], e1 = slots[i + 1], e2 = slots[i + 2], e3 = slots[i + 3];
        float n0 = rsqrtf(deg[e0.x] + 1.0f) * __int_as_float(e0.y) * dn;
        float n1 = rsqrtf(deg[e1.x] + 1.0f) * __int_as_float(e1.y) * dn;
        float n2 = rsqrtf(deg[e2.x] + 1.0f) * __int_as_float(e2.y) * dn;
        float n3 = rsqrtf(deg[e3.x] + 1.0f) * __int_as_float(e3.y) * dn;
        ushort8_t v0 = *(const ushort8_t*)(base + (size_t)e0.x * 4096);
        ushort8_t v1 = *(const ushort8_t*)(base + (size_t)e1.x * 4096);
        ushort8_t v2 = *(const ushort8_t*)(base + (size_t)e2.x * 4096);
        ushort8_t v3 = *(const ushort8_t*)(base + (size_t)e3.x * 4096);
        acc8(a2, v0, n0); acc8(a2, v1, n1); acc8(a2, v2, n2); acc8(a2, v3, n3);
    }
    for (; i < cnt; ++i) {
        int2 e0 = slots[i];
        float n0 = rsqrtf(deg[e0.x] + 1.0f) * __int_as_float(e0.y) * dn;
        ushort8_t v0 = *(const ushort8_t*)(base + (size_t)e0.x * 4096);
        acc8(a2, v0, n0);
    }

    // stage: lane l holds (bt_local = l>>2, c = (l&3)*8 .. +8)
    float* dst = &st[(wv * 16 + (l >> 2)) * 36 + (l & 3) * 8];
    *(float4*)dst       = make_float4(a2[0].x, a2[0].y, a2[1].x, a2[1].y);
    *(float4*)(dst + 4) = make_float4(a2[2].x, a2[2].y, a2[3].x, a2[3].y);
    __syncthreads();

    // each wave MFMAs its own node's 16(bt) x 32(c) tile
    float av[8];
    const float* ap = &st[(wv * 16 + colL) * 36 + q * 8];
    *(float4*)av       = *(const float4*)ap;
    *(float4*)(av + 4) = *(const float4*)(ap + 4);
    short8 Ahi, Alo;
    splitA8(av, Ahi, Alo);
    floatx4 z = { 0.f, 0.f, 0.f, 0.f };
    floatx4 acc0 = z, acc1 = z;
    acc0 = __builtin_amdgcn_mfma_f32_16x16x32_bf16(Ahi, Bhi[0], acc0, 0, 0, 0);
    acc0 = __builtin_amdgcn_mfma_f32_16x16x32_bf16(Alo, Bhi[0], acc0, 0, 0, 0);
    acc0 = __builtin_amdgcn_mfma_f32_16x16x32_bf16(Ahi, Blo[0], acc0, 0, 0, 0);
    acc1 = __builtin_amdgcn_mfma_f32_16x16x32_bf16(Ahi, Bhi[1], acc1, 0, 0, 0);
    acc1 = __builtin_amdgcn_mfma_f32_16x16x32_bf16(Alo, Bhi[1], acc1, 0, 0, 0);
    acc1 = __builtin_amdgcn_mfma_f32_16x16x32_bf16(Ahi, Blo[1], acc1, 0, 0, 0);
#pragma unroll
    for (int r = 0; r < 4; ++r) {
        int btl = q * 4 + r;
        size_t o = ((size_t)(cp * 16 + btl) * NN + n) << 5;
        out[o + colL]      = acc0[r] + gb0;
        out[o + colL + 16] = acc1[r] + gb1;
    }
}

extern "C" void kernel_launch(void* const* d_in, const int* in_sizes, int n_in,
                              void* d_out, int out_size, void* d_ws, size_t ws_size,
                              hipStream_t stream) {
    const float* x   = (const float*)d_in[0];
    const int*   ei  = (const int*)d_in[1];
    const float* ew  = (const float*)d_in[2];
    const float* g1w = (const float*)d_in[3];
    const float* g1b = (const float*)d_in[4];
    const float* g2w = (const float*)d_in[5];
    const float* g2b = (const float*)d_in[6];
    const float* gcw = (const float*)d_in[7];
    const float* gcb = (const float*)d_in[8];
    float* out = (float*)d_out;

    float* wsf      = (float*)d_ws;
    float* deg      = wsf;
    int*   cursor   = (int*)(wsf + 2048);
    int2*  pcsr     = (int2*)(wsf + 4096);
    unsigned short* h2 = (unsigned short*)(wsf + 388096);

    const int* row = ei;
    const int* col = ei + NE;

    hipMemsetAsync(wsf, 0, 4096 * sizeof(float), stream);   // deg + cursor
    hipLaunchKernelGGL(conv_deg_kernel, dim3(NCB + 157), dim3(256), 0, stream,
                       x, g1w, g1b, g2w, g2b, h2, row, col, ew,
                       deg, cursor, pcsr);
    hipLaunchKernelGGL(agg_gcn_kernel, dim3(4000), dim3(256), 0, stream,
                       h2, deg, cursor, pcsr, gcw, gcb, out);
}